// Round 3
// baseline (133.997 us; speedup 1.0000x reference)
//
#include <hip/hip_runtime.h>
#include <stdint.h>
#include <stddef.h>

// ---------------- types ----------------
typedef __attribute__((ext_vector_type(8))) short bf16x8;          // MFMA A/B frag (8 bf16)
typedef __attribute__((ext_vector_type(4))) short bf16x4;          // 8B half-frag
typedef __attribute__((ext_vector_type(4))) float f32x4;           // MFMA C/D frag

typedef const __attribute__((address_space(1))) void* gptr1_t;
typedef __attribute__((address_space(3))) void* lptr3_t;

#define GLOAD_LDS16(gp, lp) \
  __builtin_amdgcn_global_load_lds((gptr1_t)(gp), (lptr3_t)(lp), 16, 0, 0)

__device__ __forceinline__ uint16_t f2bf(float f) {
  uint32_t u = __builtin_bit_cast(uint32_t, f);
  u += 0x7fffu + ((u >> 16) & 1u);   // RNE
  return (uint16_t)(u >> 16);
}

// ---------------- problem constants ----------------
#define MB   16384      // batch
#define NP   256        // W*H positions
#define KDIM 1024       // NP*EMB
#define NDIM 1024       // OUT
#define NCLS 1024       // embedding classes

#define BM  128
#define BN  128
#define BK  64          // 16 positions per K-step
#define NK  (KDIM / BK) // 16

// ================= fragment-major tile layout =================
// A K-step tile (128 rows x 64 k) is stored as 2 halves h (32 k each).
// Each half = 512 units of 16B:  unit w = g*64 + q*16 + m
//   g = row>>4, m = row&15, q = k-quad (8 bf16) within the half.
// MFMA frag read for (g, lane=q*16+lm) = unit g*64 + lane -> lanes read
// CONSECUTIVE 16B units -> zero bank conflicts.
// Bt in HBM is pre-permuted into exactly this order per (bn, kt, h) chunk,
// so global_load_lds stays linear+coalesced on BOTH sides (rule 21).

// ---------------- kernel 1: Btf = frag-major bf16(W_dense^T) ----------------
__global__ void build_bt_kernel(const float* __restrict__ Wd,
                                uint16_t* __restrict__ Btf) {
  __shared__ uint16_t tile[32][33];               // +1 pad: no bank conflicts
  const int k0 = blockIdx.y * 32;
  const int n0 = blockIdx.x * 32;
  const int tx = threadIdx.x;                     // 0..31
  const int ty = threadIdx.y;                     // 0..7
  #pragma unroll
  for (int r = 0; r < 32; r += 8)
    tile[ty + r][tx] = f2bf(Wd[(size_t)(k0 + ty + r) * NDIM + n0 + tx]);
  __syncthreads();
  #pragma unroll
  for (int r = 0; r < 32; r += 8) {
    const int n = n0 + ty + r;                    // output col
    const int k = k0 + tx;                        // reduction index
    const int bn = n >> 7, g = (n >> 4) & 7, m = n & 15;
    const int kt = k >> 6, h = (k >> 5) & 1, q = (k >> 3) & 3, e = k & 7;
    Btf[(size_t)((bn * 16 + kt) * 2 + h) * 4096 + (size_t)(g * 64 + q * 16 + m) * 8 + e]
        = tile[tx][ty + r];
  }
}

// ---------------- kernel 2: fused embed-gather + bf16 GEMM ----------------
__global__ __launch_bounds__(256) void fused_gemm_kernel(
    const int* __restrict__ x,
    const float* __restrict__ We,
    const float* __restrict__ be,
    const uint16_t* __restrict__ Btf,
    const float* __restrict__ bias,
    float* __restrict__ C) {
  __shared__ __align__(16) uint16_t web[NCLS * 4];   // 8 KB: bf16(We[c][e]+be[e])
  __shared__ __align__(16) uint16_t As[2][4096];     // 16 KB: frag-major halves
  __shared__ __align__(16) uint16_t Bs[2][4096];     // 16 KB

  const int tid  = threadIdx.x;
  const int bm   = blockIdx.x;
  const int bn   = blockIdx.y;
  const int wave = tid >> 6;
  const int lane = tid & 63;
  const int wr   = wave >> 1;            // 2x2 wave grid, 64x64 per wave
  const int wc   = wave & 1;
  const int lm   = lane & 15;
  const int q    = lane >> 4;

  const int row0 = bm * BM;
  const int col0 = bn * BN;

  // ---- embed table -> LDS (bias folded, bf16) ----
  {
    const float4 bb = *(const float4*)be;
    #pragma unroll
    for (int c0 = 0; c0 < NCLS; c0 += 256) {
      const int c = c0 + tid;
      const float4 w = *(const float4*)(We + (size_t)c * 4);
      bf16x4 t;
      t[0] = (short)f2bf(w.x + bb.x);
      t[1] = (short)f2bf(w.y + bb.y);
      t[2] = (short)f2bf(w.z + bb.z);
      t[3] = (short)f2bf(w.w + bb.w);
      *(bf16x4*)(web + (size_t)c * 4) = t;
    }
  }

  // ---- A materialization coords ----
  const int arow = tid >> 2;             // row within 64-row half (also +64)
  const int apos = (tid & 3) * 4;        // position base in K-step (0,4,8,12)
  const int ah   = (tid >> 1) & 1;       // which 32-k half
  const int aq0  = (tid & 1) * 2;        // k-quad base within half
  const int ag   = arow >> 4;
  const int am   = arow & 15;
  uint16_t* const da = As[ah] + (size_t)((ag    ) * 64 + aq0 * 16 + am) * 8;
  uint16_t* const db = As[ah] + (size_t)((ag + 4) * 64 + aq0 * 16 + am) * 8;

  f32x4 acc[4][4];
  #pragma unroll
  for (int i = 0; i < 4; i++)
    #pragma unroll
    for (int j = 0; j < 4; j++)
      acc[i][j] = (f32x4){0.f, 0.f, 0.f, 0.f};

  const int* xr_a = x + (size_t)(row0      + arow) * NP + apos;  // rows 0..63
  const int* xr_b = x + (size_t)(row0 + 64 + arow) * NP + apos;  // rows 64..127

  // prologue: x int4 loads for kt=0 (16B, segment-coalesced)
  int4 xqa = *(const int4*)xr_a;
  int4 xqb = *(const int4*)xr_b;

  const uint16_t* const btb = Btf + (size_t)bn * (NK * 2 * 4096);  // this block's chunks

  __syncthreads();   // table ready before first gather

  for (int kt = 0; kt < NK; ++kt) {
    // ---- B staging: async global->LDS, linear on both sides ----
    const uint16_t* bsrc = btb + (size_t)kt * 2 * 4096;
    #pragma unroll
    for (int h = 0; h < 2; ++h) {
      GLOAD_LDS16(bsrc + (size_t)h * 4096 +        tid * 8, Bs[h] + tid * 8);
      GLOAD_LDS16(bsrc + (size_t)h * 4096 + 2048 + tid * 8, Bs[h] + 2048 + tid * 8);
    }

    // ---- A materialization: 8 table gathers -> 4 x 16B frag-major writes ----
    {
      union { bf16x8 v; struct { bf16x4 lo, hi; } s; } u;
      u.s.lo = *(const bf16x4*)(web + ((unsigned)xqa.x * 4u));
      u.s.hi = *(const bf16x4*)(web + ((unsigned)xqa.y * 4u));
      *(bf16x8*)(da) = u.v;
      u.s.lo = *(const bf16x4*)(web + ((unsigned)xqa.z * 4u));
      u.s.hi = *(const bf16x4*)(web + ((unsigned)xqa.w * 4u));
      *(bf16x8*)(da + 128) = u.v;                      // q+1 -> +16 units
      u.s.lo = *(const bf16x4*)(web + ((unsigned)xqb.x * 4u));
      u.s.hi = *(const bf16x4*)(web + ((unsigned)xqb.y * 4u));
      *(bf16x8*)(db) = u.v;
      u.s.lo = *(const bf16x4*)(web + ((unsigned)xqb.z * 4u));
      u.s.hi = *(const bf16x4*)(web + ((unsigned)xqb.w * 4u));
      *(bf16x8*)(db + 128) = u.v;
    }

    __syncthreads();

    // ---- x prefetch for kt+1 AFTER the drain: latency hides under MFMAs ----
    if (kt + 1 < NK) {
      xqa = *(const int4*)(xr_a + (kt + 1) * 16);
      xqb = *(const int4*)(xr_b + (kt + 1) * 16);
    }

    #pragma unroll
    for (int h = 0; h < 2; ++h) {
      bf16x8 af[4], bfr[4];
      #pragma unroll
      for (int i = 0; i < 4; i++)
        af[i] = *(const bf16x8*)(As[h] + (size_t)((wr * 4 + i) * 64 + lane) * 8);
      #pragma unroll
      for (int j = 0; j < 4; j++)
        bfr[j] = *(const bf16x8*)(Bs[h] + (size_t)((wc * 4 + j) * 64 + lane) * 8);

      #pragma unroll
      for (int i = 0; i < 4; i++)
        #pragma unroll
        for (int j = 0; j < 4; j++)
          acc[i][j] = __builtin_amdgcn_mfma_f32_16x16x32_bf16(af[i], bfr[j], acc[i][j], 0, 0, 0);
    }

    __syncthreads();
  }

  // ---- epilogue: D[row = q*4 + r][col = lm] per 16x16 frag (m89/m91-verified) ----
  float bvals[4];
  #pragma unroll
  for (int j = 0; j < 4; j++)
    bvals[j] = bias[col0 + wc * 64 + j * 16 + lm];

  #pragma unroll
  for (int i = 0; i < 4; i++) {
    const int rbase = row0 + wr * 64 + i * 16 + q * 4;
    #pragma unroll
    for (int j = 0; j < 4; j++) {
      const int col = col0 + wc * 64 + j * 16 + lm;
      #pragma unroll
      for (int r = 0; r < 4; r++)
        C[(size_t)(rbase + r) * NDIM + col] = acc[i][j][r] + bvals[j];
    }
  }
}

// ---------------- fallback (workspace too small): fp32 naive ----------------
__global__ void naive_kernel(const int* __restrict__ x,
                             const float* __restrict__ We,
                             const float* __restrict__ be,
                             const float* __restrict__ Wd,
                             const float* __restrict__ bd,
                             float* __restrict__ out) {
  __shared__ float emb[KDIM];
  const int b = blockIdx.x;
  const int tid = threadIdx.x;
  {
    const int cls = x[(size_t)b * NP + tid];
    const float4 e  = *(const float4*)(We + (size_t)cls * 4);
    const float4 bb = *(const float4*)be;
    emb[tid * 4 + 0] = e.x + bb.x;
    emb[tid * 4 + 1] = e.y + bb.y;
    emb[tid * 4 + 2] = e.z + bb.z;
    emb[tid * 4 + 3] = e.w + bb.w;
  }
  __syncthreads();
  float acc0 = bd[tid], acc1 = bd[tid + 256], acc2 = bd[tid + 512], acc3 = bd[tid + 768];
  for (int k = 0; k < KDIM; ++k) {
    const float a = emb[k];
    const float* w = Wd + (size_t)k * NDIM + tid;
    acc0 += a * w[0];
    acc1 += a * w[256];
    acc2 += a * w[512];
    acc3 += a * w[768];
  }
  float* o = out + (size_t)b * NDIM + tid;
  o[0] = acc0; o[256] = acc1; o[512] = acc2; o[768] = acc3;
}

// ---------------- launch ----------------
extern "C" void kernel_launch(void* const* d_in, const int* in_sizes, int n_in,
                              void* d_out, int out_size, void* d_ws, size_t ws_size,
                              hipStream_t stream) {
  const int*   x  = (const int*)d_in[0];
  const float* We = (const float*)d_in[1];
  const float* be = (const float*)d_in[2];
  const float* Wd = (const float*)d_in[3];
  const float* bd = (const float*)d_in[4];
  float* out = (float*)d_out;

  const size_t needB = (size_t)NDIM * KDIM * sizeof(uint16_t);  // 2 MB

  if (ws_size >= needB) {
    uint16_t* Btw = (uint16_t*)d_ws;
    build_bt_kernel<<<dim3(NDIM / 32, KDIM / 32), dim3(32, 8), 0, stream>>>(Wd, Btw);
    fused_gemm_kernel<<<dim3(MB / BM, NDIM / BN), 256, 0, stream>>>(x, We, be, Btw, bd, out);
  } else {
    naive_kernel<<<MB, 256, 0, stream>>>(x, We, be, Wd, bd, out);
  }
}

// Round 4
// 123.540 us; speedup vs baseline: 1.0846x; 1.0846x over previous
//
#include <hip/hip_runtime.h>
#include <stdint.h>
#include <stddef.h>

// ---------------- types ----------------
typedef __attribute__((ext_vector_type(8))) short bf16x8;          // MFMA A/B frag (8 bf16)
typedef __attribute__((ext_vector_type(4))) short bf16x4;          // 8B half-frag
typedef __attribute__((ext_vector_type(4))) float f32x4;           // MFMA C/D frag

typedef const __attribute__((address_space(1))) void* gptr1_t;
typedef __attribute__((address_space(3))) void* lptr3_t;

#define GLOAD_LDS16(gp, lp) \
  __builtin_amdgcn_global_load_lds((gptr1_t)(gp), (lptr3_t)(lp), 16, 0, 0)

__device__ __forceinline__ uint16_t f2bf(float f) {
  uint32_t u = __builtin_bit_cast(uint32_t, f);
  u += 0x7fffu + ((u >> 16) & 1u);   // RNE
  return (uint16_t)(u >> 16);
}

// ---------------- problem constants ----------------
#define MB   16384      // batch
#define NP   256        // W*H positions
#define KDIM 1024       // NP*EMB
#define NDIM 1024       // OUT
#define NCLS 1024       // embedding classes

#define BM  128
#define BN  256
#define BK  64          // 16 positions per K-step
#define NK  (KDIM / BK) // 16

// ================= fragment-major tile layout =================
// K-step tile stored as 2 halves h (32 k each). Each half = G*64 units of
// 16B, unit u = g*64 + q*16 + m  (g = row/16, m = row&15, q = k-quad).
// Frag read for (g, lane) = unit g*64 + lane  -> consecutive 16B units ->
// zero bank conflicts. A-writes: wave w writes units g*64 + lane (g fixed
// per write) -> consecutive -> zero conflicts. Bt is pre-permuted in HBM
// per (bn, kt, h) chunk so global_load_lds is linear on BOTH sides.

// ---------------- kernel 1: Btf = frag-major bf16(W_dense^T) ----------------
__global__ void build_bt_kernel(const float* __restrict__ Wd,
                                uint16_t* __restrict__ Btf) {
  __shared__ uint16_t tile[32][33];               // +1 pad: no bank conflicts
  const int k0 = blockIdx.y * 32;
  const int n0 = blockIdx.x * 32;
  const int tx = threadIdx.x;                     // 0..31
  const int ty = threadIdx.y;                     // 0..7
  #pragma unroll
  for (int r = 0; r < 32; r += 8)
    tile[ty + r][tx] = f2bf(Wd[(size_t)(k0 + ty + r) * NDIM + n0 + tx]);
  __syncthreads();
  #pragma unroll
  for (int r = 0; r < 32; r += 8) {
    const int n = n0 + ty + r;                    // output col
    const int k = k0 + tx;                        // reduction index
    const int bn = n >> 8, g = (n >> 4) & 15, m = n & 15;
    const int kt = k >> 6, h = (k >> 5) & 1, q = (k >> 3) & 3, e = k & 7;
    Btf[(size_t)((bn * 16 + kt) * 2 + h) * 8192 + (size_t)(g * 64 + q * 16 + m) * 8 + e]
        = tile[tx][ty + r];
  }
}

// ---------------- kernel 2: fused embed-gather + bf16 GEMM ----------------
// 512 threads, wave grid 2(M)x4(N), 128x256 per block, grid 128x4.
// A-tile gathered once per block -> shared by 256 output cols (was 128).
__global__ __launch_bounds__(512) void fused_gemm_kernel(
    const int* __restrict__ x,
    const float* __restrict__ We,
    const float* __restrict__ be,
    const uint16_t* __restrict__ Btf,
    const float* __restrict__ bias,
    float* __restrict__ C) {
  __shared__ __align__(16) uint16_t web[NCLS * 4];   // 8 KB: bf16(We[c][e]+be[e])
  __shared__ __align__(16) uint16_t As[2 * 4096];    // 16 KB: frag-major halves (g<8)
  __shared__ __align__(16) uint16_t Bs[2 * 8192];    // 32 KB: frag-major halves (g<16)

  const int tid  = threadIdx.x;
  const int bm   = blockIdx.x;
  const int bn   = blockIdx.y;
  const int w    = tid >> 6;
  const int l    = tid & 63;
  const int wr   = w >> 2;               // 0..1  (64-row band)
  const int wc   = w & 3;                // 0..3  (64-col band)
  const int lm   = l & 15;
  const int q4   = l >> 4;

  const int row0 = bm * BM;
  const int col0 = bn * BN;

  // ---- embed table -> LDS (bias folded, bf16) ----
  {
    const float4 bb = *(const float4*)be;
    #pragma unroll
    for (int c0 = 0; c0 < NCLS; c0 += 512) {
      const int c = c0 + tid;
      const float4 wv = *(const float4*)(We + (size_t)c * 4);
      bf16x4 t;
      t[0] = (short)f2bf(wv.x + bb.x);
      t[1] = (short)f2bf(wv.y + bb.y);
      t[2] = (short)f2bf(wv.z + bb.z);
      t[3] = (short)f2bf(wv.w + bb.w);
      *(bf16x4*)(web + (size_t)c * 4) = t;
    }
  }

  // ---- A materialization coords: thread owns 2 units (s=0,1) ----
  // unit (h=mh, g=gb+s, q=q4, m=lm):  row = g*16+lm,  pos = kt*16 + mh*8 + q4*2
  const int mh = w >> 2;                 // k-half this wave fills
  const int gb = (w & 3) * 2;           // g base (0,2,4,6)
  uint16_t* const dA0 = As + (size_t)mh * 4096 + (size_t)((gb    ) * 64 + l) * 8;
  uint16_t* const dA1 = As + (size_t)mh * 4096 + (size_t)((gb + 1) * 64 + l) * 8;
  const int* xr0 = x + (size_t)(row0 + (gb    ) * 16 + lm) * NP + mh * 8 + q4 * 2;
  const int* xr1 = x + (size_t)(row0 + (gb + 1) * 16 + lm) * NP + mh * 8 + q4 * 2;

  f32x4 acc[4][4];
  #pragma unroll
  for (int i = 0; i < 4; i++)
    #pragma unroll
    for (int j = 0; j < 4; j++)
      acc[i][j] = (f32x4){0.f, 0.f, 0.f, 0.f};

  // prologue: class pairs for kt=0 (8B aligned int2)
  int2 xq0 = *(const int2*)xr0;
  int2 xq1 = *(const int2*)xr1;

  const uint16_t* const btb = Btf + (size_t)bn * (NK * 16384);  // this block's chunks

  __syncthreads();   // table ready before first gather

  for (int kt = 0; kt < NK; ++kt) {
    // ---- B staging: async global->LDS, linear on both sides ----
    const uint16_t* bsrc = btb + (size_t)kt * 16384;
    #pragma unroll
    for (int r = 0; r < 4; ++r)
      GLOAD_LDS16(bsrc + (size_t)r * 4096 + tid * 8, Bs + (size_t)r * 4096 + tid * 8);

    // ---- A materialization: 4 table gathers -> 2 x 16B conflict-free writes ----
    {
      union { bf16x8 v; struct { bf16x4 lo, hi; } s; } u;
      u.s.lo = *(const bf16x4*)(web + ((unsigned)xq0.x * 4u));
      u.s.hi = *(const bf16x4*)(web + ((unsigned)xq0.y * 4u));
      *(bf16x8*)(dA0) = u.v;
      u.s.lo = *(const bf16x4*)(web + ((unsigned)xq1.x * 4u));
      u.s.hi = *(const bf16x4*)(web + ((unsigned)xq1.y * 4u));
      *(bf16x8*)(dA1) = u.v;
    }

    __syncthreads();

    // ---- x prefetch for kt+1 AFTER the drain: latency hides under MFMAs ----
    if (kt + 1 < NK) {
      xq0 = *(const int2*)(xr0 + (kt + 1) * 16);
      xq1 = *(const int2*)(xr1 + (kt + 1) * 16);
    }

    #pragma unroll
    for (int h = 0; h < 2; ++h) {
      bf16x8 af[4], bfr[4];
      #pragma unroll
      for (int i = 0; i < 4; i++)
        af[i] = *(const bf16x8*)(As + (size_t)h * 4096 + (size_t)((wr * 4 + i) * 64 + l) * 8);
      #pragma unroll
      for (int j = 0; j < 4; j++)
        bfr[j] = *(const bf16x8*)(Bs + (size_t)h * 8192 + (size_t)((wc * 4 + j) * 64 + l) * 8);

      #pragma unroll
      for (int i = 0; i < 4; i++)
        #pragma unroll
        for (int j = 0; j < 4; j++)
          acc[i][j] = __builtin_amdgcn_mfma_f32_16x16x32_bf16(af[i], bfr[j], acc[i][j], 0, 0, 0);
    }

    __syncthreads();
  }

  // ---- epilogue: D[row = q4*4 + r][col = lm] per 16x16 frag (m89/m91-verified) ----
  float bvals[4];
  #pragma unroll
  for (int j = 0; j < 4; j++)
    bvals[j] = bias[col0 + wc * 64 + j * 16 + lm];

  #pragma unroll
  for (int i = 0; i < 4; i++) {
    const int rbase = row0 + wr * 64 + i * 16 + q4 * 4;
    #pragma unroll
    for (int j = 0; j < 4; j++) {
      const int col = col0 + wc * 64 + j * 16 + lm;
      #pragma unroll
      for (int r = 0; r < 4; r++)
        C[(size_t)(rbase + r) * NDIM + col] = acc[i][j][r] + bvals[j];
    }
  }
}

// ---------------- fallback (workspace too small): fp32 naive ----------------
__global__ void naive_kernel(const int* __restrict__ x,
                             const float* __restrict__ We,
                             const float* __restrict__ be,
                             const float* __restrict__ Wd,
                             const float* __restrict__ bd,
                             float* __restrict__ out) {
  __shared__ float emb[KDIM];
  const int b = blockIdx.x;
  const int tid = threadIdx.x;
  {
    const int cls = x[(size_t)b * NP + tid];
    const float4 e  = *(const float4*)(We + (size_t)cls * 4);
    const float4 bb = *(const float4*)be;
    emb[tid * 4 + 0] = e.x + bb.x;
    emb[tid * 4 + 1] = e.y + bb.y;
    emb[tid * 4 + 2] = e.z + bb.z;
    emb[tid * 4 + 3] = e.w + bb.w;
  }
  __syncthreads();
  float acc0 = bd[tid], acc1 = bd[tid + 256], acc2 = bd[tid + 512], acc3 = bd[tid + 768];
  for (int k = 0; k < KDIM; ++k) {
    const float a = emb[k];
    const float* wv = Wd + (size_t)k * NDIM + tid;
    acc0 += a * wv[0];
    acc1 += a * wv[256];
    acc2 += a * wv[512];
    acc3 += a * wv[768];
  }
  float* o = out + (size_t)b * NDIM + tid;
  o[0] = acc0; o[256] = acc1; o[512] = acc2; o[768] = acc3;
}

// ---------------- launch ----------------
extern "C" void kernel_launch(void* const* d_in, const int* in_sizes, int n_in,
                              void* d_out, int out_size, void* d_ws, size_t ws_size,
                              hipStream_t stream) {
  const int*   x  = (const int*)d_in[0];
  const float* We = (const float*)d_in[1];
  const float* be = (const float*)d_in[2];
  const float* Wd = (const float*)d_in[3];
  const float* bd = (const float*)d_in[4];
  float* out = (float*)d_out;

  const size_t needB = (size_t)NDIM * KDIM * sizeof(uint16_t);  // 2 MB

  if (ws_size >= needB) {
    uint16_t* Btw = (uint16_t*)d_ws;
    build_bt_kernel<<<dim3(NDIM / 32, KDIM / 32), dim3(32, 8), 0, stream>>>(Wd, Btw);
    fused_gemm_kernel<<<dim3(MB / BM, NDIM / BN), 512, 0, stream>>>(x, We, be, Btw, bd, out);
  } else {
    naive_kernel<<<MB, 256, 0, stream>>>(x, We, be, Wd, bd, out);
  }
}

// Round 5
// 117.328 us; speedup vs baseline: 1.1421x; 1.0529x over previous
//
#include <hip/hip_runtime.h>
#include <stdint.h>
#include <stddef.h>

// ---------------- types ----------------
typedef __attribute__((ext_vector_type(8))) short bf16x8;          // MFMA A/B frag (8 bf16)
typedef __attribute__((ext_vector_type(4))) short bf16x4;          // 8B half-frag
typedef __attribute__((ext_vector_type(4))) float f32x4;           // MFMA C/D frag

typedef const __attribute__((address_space(1))) void* gptr1_t;
typedef __attribute__((address_space(3))) void* lptr3_t;

#define GLOAD_LDS16(gp, lp) \
  __builtin_amdgcn_global_load_lds((gptr1_t)(gp), (lptr3_t)(lp), 16, 0, 0)

#define VMWAIT(N)  asm volatile("s_waitcnt vmcnt(" #N ")" ::: "memory")
#define MEMFENCE() asm volatile("" ::: "memory")

__device__ __forceinline__ uint16_t f2bf(float f) {
  uint32_t u = __builtin_bit_cast(uint32_t, f);
  u += 0x7fffu + ((u >> 16) & 1u);   // RNE
  return (uint16_t)(u >> 16);
}

// ---------------- problem constants ----------------
#define MB   16384      // batch
#define NP   256        // W*H positions
#define KDIM 1024       // NP*EMB
#define NDIM 1024       // OUT
#define NCLS 1024       // embedding classes

#define BM  128
#define BN  256
#define NH  32          // half-steps: 32 k each (16 K-tiles x 2 halves)

// ================= fragment-major tile layout =================
// Each 32-k half-tile = G*64 units of 16B, unit u = g*64 + q*16 + m
//   (g = row/16, m = row&15, q = k-quad). Frag read for (g, lane) = unit
// g*64 + lane -> consecutive 16B -> zero bank conflicts. A-writes: thread
// tid writes unit tid -> consecutive -> zero conflicts. Bt is pre-permuted
// in HBM per (bn, s) half-chunk so global_load_lds is linear on BOTH sides.

// ---------------- kernel 1: Btf = frag-major bf16(W_dense^T) ----------------
__global__ void build_bt_kernel(const float* __restrict__ Wd,
                                uint16_t* __restrict__ Btf) {
  __shared__ uint16_t tile[32][33];               // +1 pad: no bank conflicts
  const int k0 = blockIdx.y * 32;
  const int n0 = blockIdx.x * 32;
  const int tx = threadIdx.x;                     // 0..31
  const int ty = threadIdx.y;                     // 0..7
  #pragma unroll
  for (int r = 0; r < 32; r += 8)
    tile[ty + r][tx] = f2bf(Wd[(size_t)(k0 + ty + r) * NDIM + n0 + tx]);
  __syncthreads();
  #pragma unroll
  for (int r = 0; r < 32; r += 8) {
    const int n = n0 + ty + r;                    // output col
    const int k = k0 + tx;                        // reduction index
    const int bn = n >> 8, g = (n >> 4) & 15, m = n & 15;
    const int s = k >> 5, q = (k >> 3) & 3, e = k & 7;   // half-step, k-quad, elem
    Btf[(size_t)(bn * NH + s) * 8192 + (size_t)(g * 64 + q * 16 + m) * 8 + e]
        = tile[tx][ty + r];
  }
}

// ---------------- fused kernel helpers ----------------
__device__ __forceinline__ void amat_write(const uint16_t* web, uint16_t* dst, int2 cls) {
  union { bf16x8 v; struct { bf16x4 lo, hi; } s; } u;
  u.s.lo = *(const bf16x4*)(web + ((unsigned)cls.x * 4u));
  u.s.hi = *(const bf16x4*)(web + ((unsigned)cls.y * 4u));
  *(bf16x8*)dst = u.v;
}

__device__ __forceinline__ void compute_half(const uint16_t* Asb, const uint16_t* Bsb,
                                             int wr, int wc, int l, f32x4 acc[4][4]) {
  bf16x8 af[4], bfr[4];
  #pragma unroll
  for (int i = 0; i < 4; i++)
    af[i] = *(const bf16x8*)(Asb + (size_t)((wr * 4 + i) * 64 + l) * 8);
  #pragma unroll
  for (int j = 0; j < 4; j++)
    bfr[j] = *(const bf16x8*)(Bsb + (size_t)((wc * 4 + j) * 64 + l) * 8);

  __builtin_amdgcn_s_setprio(1);
  #pragma unroll
  for (int i = 0; i < 4; i++)
    #pragma unroll
    for (int j = 0; j < 4; j++)
      acc[i][j] = __builtin_amdgcn_mfma_f32_16x16x32_bf16(af[i], bfr[j], acc[i][j], 0, 0, 0);
  __builtin_amdgcn_s_setprio(0);
}

// ---------------- kernel 2: fused embed-gather + bf16 GEMM, pipelined ----------------
// 512 threads, wave grid 2(M)x4(N), 128x256 per block, grid 128x4, 2 blocks/CU.
// 32 half-steps, double-buffered halves, staging issued AFTER the barrier so
// it overlaps the previous half's compute; counted vmcnt (never 0 mid-loop).
__global__ __launch_bounds__(512) void fused_gemm_kernel(
    const int* __restrict__ x,
    const float* __restrict__ We,
    const float* __restrict__ be,
    const uint16_t* __restrict__ Btf,
    const float* __restrict__ bias,
    float* __restrict__ C) {
  __shared__ __align__(16) uint16_t web[NCLS * 4];   // 8 KB: bf16(We[c][e]+be[e])
  __shared__ __align__(16) uint16_t As3[2 * 4096];   // 16 KB: 2 half-buffers
  __shared__ __align__(16) uint16_t Bs3[2 * 8192];   // 32 KB: 2 half-buffers

  const int tid  = threadIdx.x;
  const int bm   = blockIdx.x;
  const int bn   = blockIdx.y;
  const int w    = tid >> 6;
  const int l    = tid & 63;
  const int wr   = w >> 2;               // 0..1  (64-row band)
  const int wc   = w & 3;                // 0..3  (64-col band)
  const int lm   = l & 15;
  const int q4   = l >> 4;

  const int row0 = bm * BM;
  const int col0 = bn * BN;

  // ---- embed table -> LDS (bias folded, bf16) ----
  {
    const float4 bb = *(const float4*)be;
    #pragma unroll
    for (int c0 = 0; c0 < NCLS; c0 += 512) {
      const int c = c0 + tid;
      const float4 wv = *(const float4*)(We + (size_t)c * 4);
      bf16x4 t;
      t[0] = (short)f2bf(wv.x + bb.x);
      t[1] = (short)f2bf(wv.y + bb.y);
      t[2] = (short)f2bf(wv.z + bb.z);
      t[3] = (short)f2bf(wv.w + bb.w);
      *(bf16x4*)(web + (size_t)c * 4) = t;
    }
  }

  f32x4 acc[4][4];
  #pragma unroll
  for (int i = 0; i < 4; i++)
    #pragma unroll
    for (int j = 0; j < 4; j++)
      acc[i][j] = (f32x4){0.f, 0.f, 0.f, 0.f};

  // thread tid owns unit tid of each A half: row = w*16+lm, k-quad q4
  const int* xrow = x + (size_t)(row0 + w * 16 + lm) * NP + q4 * 2;
  const uint16_t* const btb = Btf + (size_t)bn * (NH * 8192);

  // ---- prologue ----
  int2 xq0    = *(const int2*)(xrow);        // x for half 0
  int2 xq_next = *(const int2*)(xrow + 8);   // x for half 1
  __syncthreads();                            // table visible (full drain, once)

  GLOAD_LDS16(btb + tid * 8,        Bs3 + tid * 8);
  GLOAD_LDS16(btb + 4096 + tid * 8, Bs3 + 4096 + tid * 8);
  amat_write(web, As3 + tid * 8, xq0);
  asm volatile("s_waitcnt lgkmcnt(0)" ::: "memory");  // A(0) visible before sigma_0

  // ---- main loop: s = 0..29 ----
  for (int s = 0; s < 30; ++s) {
    const int cb = s & 1, nb = cb ^ 1;
    int2 xu = xq_next;                               // x(s+1)
    xq_next = *(const int2*)(xrow + (s + 2) * 8);    // x(s+2), newest vmem
    VMWAIT(1);                                       // B(s) landed; x(s+2) in flight
    MEMFENCE();
    __builtin_amdgcn_s_barrier();
    MEMFENCE();
    // stage s+1 (overlaps compute(s)); buf nb last read before the barrier
    const uint16_t* bsrc = btb + (size_t)(s + 1) * 8192;
    GLOAD_LDS16(bsrc + tid * 8,        Bs3 + (size_t)nb * 8192 + tid * 8);
    GLOAD_LDS16(bsrc + 4096 + tid * 8, Bs3 + (size_t)nb * 8192 + 4096 + tid * 8);
    amat_write(web, As3 + (size_t)nb * 4096 + tid * 8, xu);
    compute_half(As3 + (size_t)cb * 4096, Bs3 + (size_t)cb * 8192, wr, wc, l, acc);
  }

  // ---- peeled s = 30 (no x-load) ----
  {
    int2 xu = xq_next;                               // x(31)
    VMWAIT(0);                                       // B(30) landed, nothing newer
    MEMFENCE();
    __builtin_amdgcn_s_barrier();
    MEMFENCE();
    const uint16_t* bsrc = btb + (size_t)31 * 8192;
    GLOAD_LDS16(bsrc + tid * 8,        Bs3 + 8192 + tid * 8);
    GLOAD_LDS16(bsrc + 4096 + tid * 8, Bs3 + 8192 + 4096 + tid * 8);
    amat_write(web, As3 + 4096 + tid * 8, xu);
    compute_half(As3, Bs3, wr, wc, l, acc);          // s=30: cb=0
  }

  // ---- peeled s = 31 ----
  VMWAIT(0);
  MEMFENCE();
  __builtin_amdgcn_s_barrier();
  MEMFENCE();
  compute_half(As3 + 4096, Bs3 + 8192, wr, wc, l, acc);  // cb=1

  // ---- epilogue: D[row = q4*4 + r][col = lm] per 16x16 frag (m89/m91-verified) ----
  float bvals[4];
  #pragma unroll
  for (int j = 0; j < 4; j++)
    bvals[j] = bias[col0 + wc * 64 + j * 16 + lm];

  #pragma unroll
  for (int i = 0; i < 4; i++) {
    const int rbase = row0 + wr * 64 + i * 16 + q4 * 4;
    #pragma unroll
    for (int j = 0; j < 4; j++) {
      const int col = col0 + wc * 64 + j * 16 + lm;
      #pragma unroll
      for (int r = 0; r < 4; r++)
        C[(size_t)(rbase + r) * NDIM + col] = acc[i][j][r] + bvals[j];
    }
  }
}

// ---------------- fallback (workspace too small): fp32 naive ----------------
__global__ void naive_kernel(const int* __restrict__ x,
                             const float* __restrict__ We,
                             const float* __restrict__ be,
                             const float* __restrict__ Wd,
                             const float* __restrict__ bd,
                             float* __restrict__ out) {
  __shared__ float emb[KDIM];
  const int b = blockIdx.x;
  const int tid = threadIdx.x;
  {
    const int cls = x[(size_t)b * NP + tid];
    const float4 e  = *(const float4*)(We + (size_t)cls * 4);
    const float4 bb = *(const float4*)be;
    emb[tid * 4 + 0] = e.x + bb.x;
    emb[tid * 4 + 1] = e.y + bb.y;
    emb[tid * 4 + 2] = e.z + bb.z;
    emb[tid * 4 + 3] = e.w + bb.w;
  }
  __syncthreads();
  float acc0 = bd[tid], acc1 = bd[tid + 256], acc2 = bd[tid + 512], acc3 = bd[tid + 768];
  for (int k = 0; k < KDIM; ++k) {
    const float a = emb[k];
    const float* wv = Wd + (size_t)k * NDIM + tid;
    acc0 += a * wv[0];
    acc1 += a * wv[256];
    acc2 += a * wv[512];
    acc3 += a * wv[768];
  }
  float* o = out + (size_t)b * NDIM + tid;
  o[0] = acc0; o[256] = acc1; o[512] = acc2; o[768] = acc3;
}

// ---------------- launch ----------------
extern "C" void kernel_launch(void* const* d_in, const int* in_sizes, int n_in,
                              void* d_out, int out_size, void* d_ws, size_t ws_size,
                              hipStream_t stream) {
  const int*   x  = (const int*)d_in[0];
  const float* We = (const float*)d_in[1];
  const float* be = (const float*)d_in[2];
  const float* Wd = (const float*)d_in[3];
  const float* bd = (const float*)d_in[4];
  float* out = (float*)d_out;

  const size_t needB = (size_t)NDIM * KDIM * sizeof(uint16_t);  // 2 MB

  if (ws_size >= needB) {
    uint16_t* Btw = (uint16_t*)d_ws;
    build_bt_kernel<<<dim3(NDIM / 32, KDIM / 32), dim3(32, 8), 0, stream>>>(Wd, Btw);
    fused_gemm_kernel<<<dim3(MB / BM, NDIM / BN), 512, 0, stream>>>(x, We, be, Btw, bd, out);
  } else {
    naive_kernel<<<MB, 256, 0, stream>>>(x, We, be, Wd, bd, out);
  }
}